// Round 4
// baseline (680.238 us; speedup 1.0000x reference)
//
#include <hip/hip_runtime.h>
#include <hip/hip_bf16.h>
#include <math.h>

typedef unsigned short ushort_t;
typedef __attribute__((ext_vector_type(8))) short bfrag;   // 8 bf16 = 4 VGPRs
typedef __attribute__((ext_vector_type(4))) float ffrag;   // 4 fp32 acc

// ---------------- problem constants ----------------
constexpr int N_NODES = 100000;
constexpr int N_EDGES = 800000;
constexpr int NB      = 64;
constexpr int IN_F    = 256;
constexpr int HC1C    = 128;
constexpr int HC2C    = 32;
constexpr int SA_D    = 350;
constexpr float NEG   = 0.2f;

constexpr int SCAN_NBLK = (N_NODES + 255) / 256;  // 391
constexpr int MB64      = (N_NODES + 63) / 64;    // 1563

// ---------------- workspace layout (float-sized slots) ----------------
constexpr size_t OFF_WT1    = 0;                                   // 256*256 ush
constexpr size_t OFF_WT2    = OFF_WT1 + 65536;
constexpr size_t OFF_WT3    = OFF_WT2 + 16384;
constexpr size_t OFF_BC1    = OFF_WT3 + 4096;                      // 256
constexpr size_t OFF_BC2    = OFF_BC1 + 256;                       // 128
constexpr size_t OFF_BC3    = OFF_BC2 + 128;                       // 64
constexpr size_t OFF_XLR    = OFF_BC3 + 64;                        // N*256 bf16
constexpr size_t OFF_H      = OFF_XLR + (size_t)N_NODES * 256;     // N*128 bf16
constexpr size_t OFF_DEG    = OFF_H + (size_t)N_NODES * 128;       // N ints
constexpr size_t OFF_ROWPTR = OFF_DEG + N_NODES;                   // N+1 ints
constexpr size_t OFF_CURSOR = OFF_ROWPTR + N_NODES + 1;            // N ints
constexpr size_t OFF_BLKS   = OFF_CURSOR + N_NODES;                // 512 ints
constexpr size_t OFF_BLKO   = OFF_BLKS + 512;                      // 512 ints
constexpr size_t OFF_CSRSRC = OFF_BLKO + 512;                      // E ints
constexpr size_t OFF_POOLED = OFF_CSRSRC + N_EDGES;                // 64*32
constexpr size_t OFF_CNT    = OFF_POOLED + NB * HC2C;              // 64
constexpr size_t WS_FLOATS  = OFF_CNT + NB;

// ---------------- bf16 helpers ----------------
__device__ __forceinline__ ushort_t f2bf(float f) {  // RNE
  union { float f; unsigned int u; } a;
  a.f = f;
  unsigned int r = a.u + 0x7FFFu + ((a.u >> 16) & 1u);
  return (ushort_t)(r >> 16);
}
__device__ __forceinline__ float bf2f(ushort_t h) {
  union { unsigned int u; float f; } a;
  a.u = ((unsigned int)h) << 16;
  return a.f;
}
__device__ __forceinline__ float2 bfp(unsigned int u) {
  float2 r;
  r.x = __uint_as_float(u << 16);
  r.y = __uint_as_float(u & 0xFFFF0000u);
  return r;
}
__device__ __forceinline__ unsigned int pack2(float a, float b) {
  unsigned int ua = __float_as_uint(a);
  ua += 0x7FFFu + ((ua >> 16) & 1u);
  unsigned int ub = __float_as_uint(b);
  ub += 0x7FFFu + ((ub >> 16) & 1u);
  return __builtin_amdgcn_perm(ub, ua, 0x07060302u);
}
__device__ __forceinline__ void unp8(uint4 u, float* x) {
  float2 p0 = bfp(u.x), p1 = bfp(u.y), p2 = bfp(u.z), p3 = bfp(u.w);
  x[0] = p0.x; x[1] = p0.y; x[2] = p1.x; x[3] = p1.y;
  x[4] = p2.x; x[5] = p2.y; x[6] = p3.x; x[7] = p3.y;
}

// ---------------- fused weight fold/pack ----------------
__global__ void k_pack_all(const float* __restrict__ Wv, const float* __restrict__ bv,
                           const float* __restrict__ Wl1, const float* __restrict__ bl1,
                           const float* __restrict__ Wr1, const float* __restrict__ br1,
                           const float* __restrict__ Wl2, const float* __restrict__ bl2,
                           const float* __restrict__ Wr2, const float* __restrict__ br2,
                           const float* __restrict__ Wl3, const float* __restrict__ bl3,
                           const float* __restrict__ Wr3, const float* __restrict__ br3,
                           ushort_t* __restrict__ WT1, float* __restrict__ bc1,
                           ushort_t* __restrict__ WT2, float* __restrict__ bc2,
                           ushort_t* __restrict__ WT3, float* __restrict__ bc3) {
  int blk = blockIdx.x;
  int tid = threadIdx.x;
  if (blk < 256) {            // WT1 fold: (Wv@W{l,r}1)^T
    int t = blk * 256 + tid;
    int n = t & 255, k = t >> 8;
    const float* Wx = (n < 128) ? Wl1 : Wr1;
    int j = n & 127;
    float a = 0.f;
    for (int kk = 0; kk < SA_D; ++kk) a += Wv[k * SA_D + kk] * Wx[kk * 128 + j];
    WT1[(size_t)n * 256 + k] = f2bf(a);
  } else if (blk == 256) {    // bc1
    int n = tid;
    const float* Wx = (n < 128) ? Wl1 : Wr1;
    const float* bx = (n < 128) ? bl1 : br1;
    int j = n & 127;
    float a = bx[j];
    for (int kk = 0; kk < SA_D; ++kk) a += bv[kk] * Wx[kk * 128 + j];
    bc1[n] = a;
  } else if (blk < 321) {     // WT2 transpose pack
    int t = (blk - 257) * 256 + tid;
    int n = t & 127, k = t >> 7;
    if (t < 128) bc2[t] = (t < 64) ? bl2[t] : br2[t - 64];
    float v = (n < 64) ? Wl2[k * 64 + n] : Wr2[k * 64 + (n - 64)];
    WT2[(size_t)n * 128 + k] = f2bf(v);
  } else {                    // WT3 transpose pack
    int t = (blk - 321) * 256 + tid;
    int n = t & 63, k = t >> 6;
    if (t < 64) bc3[t] = (t < 32) ? bl3[t] : br3[t - 32];
    float v = (n < 32) ? Wl3[k * 32 + n] : Wr3[k * 32 + (n - 32)];
    WT3[(size_t)n * 64 + k] = f2bf(v);
  }
}

// ---------------- CSR build ----------------
__global__ void k_hist(const int* __restrict__ dst, int* __restrict__ deg) {
  int e = blockIdx.x * blockDim.x + threadIdx.x;
  if (e < N_EDGES) atomicAdd(deg + dst[e], 1);
}

__global__ void k_scan_local(const int* __restrict__ deg, int* __restrict__ row_ptr,
                             int* __restrict__ blk_sum) {
  __shared__ int sh[256];
  int t = threadIdx.x;
  int i = blockIdx.x * 256 + t;
  int v = (i < N_NODES) ? deg[i] : 0;
  sh[t] = v;
  __syncthreads();
  for (int off = 1; off < 256; off <<= 1) {
    int add = (t >= off) ? sh[t - off] : 0;
    __syncthreads();
    sh[t] += add;
    __syncthreads();
  }
  if (i < N_NODES) row_ptr[i] = sh[t] - v;
  if (t == 255) blk_sum[blockIdx.x] = sh[255];
}

__global__ void k_scan_blk(const int* __restrict__ blk_sum, int* __restrict__ blk_off) {
  __shared__ int sh[512];
  int t = threadIdx.x;
  int v = (t < SCAN_NBLK) ? blk_sum[t] : 0;
  sh[t] = v;
  __syncthreads();
  for (int off = 1; off < 512; off <<= 1) {
    int add = (t >= off) ? sh[t - off] : 0;
    __syncthreads();
    sh[t] += add;
    __syncthreads();
  }
  blk_off[t] = sh[t] - v;
}

__global__ void k_scan_add(int* __restrict__ row_ptr, const int* __restrict__ blk_off,
                           int* __restrict__ cursor) {
  int i = blockIdx.x * blockDim.x + threadIdx.x;
  if (i < N_NODES) {
    int v = row_ptr[i] + blk_off[i >> 8];
    row_ptr[i] = v;
    cursor[i] = v;
  }
  if (i == 0) row_ptr[N_NODES] = N_EDGES;
}

__global__ void k_fill(const int* __restrict__ src, const int* __restrict__ dst,
                       int* __restrict__ cursor, int* __restrict__ csr_src) {
  int e = blockIdx.x * blockDim.x + threadIdx.x;
  if (e >= N_EDGES) return;
  int pos = atomicAdd(cursor + dst[e], 1);
  csr_src[pos] = src[e];
}

// ---------------- reg-staged double-buffered MFMA GEMM ----------------
// Four structures benched: r0 per-step/no-overlap 75us@45%occ; r1 reg-stream
// 93us@18%; r2 gl_lds 2-phase 80us@25% (gl_lds forces fp32 A in LDS = 48KB,
// AND __syncthreads drains vmcnt(0) for gl_lds); r3 whole-K 103us@38%
// (B-latency-bound loop).  Lesson: need BOTH high residency AND latency
// overlap.  This structure (T14 async-STAGE, G15):
//  * plain global_load -> VGPR slots (NOT drained by __syncthreads; compiler
//    emits exact counted vmcnt before the use)
//  * tile t lives in slot[t&1]; iter i: issue load(i+2), compute(i),
//    convert+ds_write(i+1), ONE barrier.  Load window = 2 compute phases.
//  * fp32->bf16 convert happens in regs BEFORE ds_write -> LDS buffers are
//    bf16-compact: (A 4KB + B 8KB) x 2 = 24KB -> 4-5 blocks/CU; each wave
//    holds 2 staged tiles in regs -> >=128KB outstanding bytes per CU.
//  * r2's proven XOR-granule swizzle (line=2 rows=8 granules, g^(line&7))
//    -> ds_read_b128 fragments ~conflict-free (4.8M -> ~0.8M).
// Tile/fragment/k-order/pack2/acc chain identical to r0 -> bit-identical.
template <int K, int NN, int BN, bool AF32>
__global__ __launch_bounds__(256, 4) void k_gemm_bf16(const void* __restrict__ xin,
                                                      const ushort_t* __restrict__ WT,
                                                      const float* __restrict__ bc,
                                                      ushort_t* __restrict__ out, int M) {
  constexpr int RT  = 2;             // 16-row tiles per wave
  constexpr int CT  = BN / 32;       // n-tiles per wave (colgroup = BN/2)
  constexpr int NK  = K / 32;        // k-steps
  constexpr int BGT = BN / 64;       // B 16B-granules per thread per step
  constexpr int BUS = 2048 + BN * 32;  // ushorts per LDS buffer (A 4KB + B)
  __shared__ __align__(16) ushort_t lds[2][BUS];

  const int tid  = threadIdx.x;
  const int wave = tid >> 6;
  const int lane = tid & 63;
  const int quad = lane >> 4;
  const int l16  = lane & 15;
  const int wrow = wave >> 1;
  const int wcol = wave & 1;
  const int m0   = blockIdx.x * 64;
  const int n0   = blockIdx.y * BN;

  const float*    af32 = (const float*)xin;
  const ushort_t* ab16 = (const ushort_t*)xin;

  // ---- staging indices: thread -> one A granule + BGT B granules ----
  // granule = 16B bf16 = 8 k-elems; line = 128B = 2 rows; phys = lg^(line&7)
  const int aline = tid >> 3, alg = tid & 7;
  const int arow  = aline * 2 + (alg >> 2);
  int am = m0 + arow;
  if (am >= M) am = M - 1;
  const size_t aoff = (size_t)am * K + (alg & 3) * 8;
  const int awi = aline * 64 + ((alg ^ (aline & 7)) * 8);

  size_t boff[BGT];
  int    bwi[BGT];
#pragma unroll
  for (int g = 0; g < BGT; ++g) {
    const int sB = g * 256 + tid;
    const int bline = sB >> 3, blg = sB & 7;
    const int brow = bline * 2 + (blg >> 2);
    boff[g] = (size_t)(n0 + brow) * K + (blg & 3) * 8;
    bwi[g]  = 2048 + bline * 64 + ((blg ^ (bline & 7)) * 8);
  }

  // ---- fragment read offsets (r2-proven mapping) ----
  int ard[RT];
#pragma unroll
  for (int rt = 0; rt < RT; ++rt) {
    const int row = wrow * 32 + rt * 16 + l16;
    const int line = row >> 1;
    ard[rt] = line * 64 + ((((row & 1) * 4 + quad) ^ (line & 7)) * 8);
  }
  int brd[CT];
#pragma unroll
  for (int ct = 0; ct < CT; ++ct) {
    const int rowb = wcol * (BN / 2) + ct * 16 + l16;
    const int lineb = rowb >> 1;
    brd[ct] = 2048 + lineb * 64 + ((((rowb & 1) * 4 + quad) ^ (lineb & 7)) * 8);
  }

  // ---- register slots: tile t lives in slot[t&1] ----
  float4 sf[2][2];
  uint4  sh[2];
  uint4  sb[2][BGT];

  auto LOAD = [&](int ks, int s) {
    if (AF32) {
      sf[s][0] = *(const float4*)(af32 + aoff + (size_t)ks * 32);
      sf[s][1] = *(const float4*)(af32 + aoff + (size_t)ks * 32 + 4);
    } else {
      sh[s] = *(const uint4*)(ab16 + aoff + (size_t)ks * 32);
    }
#pragma unroll
    for (int g = 0; g < BGT; ++g)
      sb[s][g] = *(const uint4*)(WT + boff[g] + (size_t)ks * 32);
  };
  auto WRITE = [&](int s, int b) {
    uint4 w;
    if (AF32) {
      w.x = pack2(sf[s][0].x, sf[s][0].y);
      w.y = pack2(sf[s][0].z, sf[s][0].w);
      w.z = pack2(sf[s][1].x, sf[s][1].y);
      w.w = pack2(sf[s][1].z, sf[s][1].w);
    } else {
      w = sh[s];
    }
    *(uint4*)&lds[b][awi] = w;
#pragma unroll
    for (int g = 0; g < BGT; ++g) *(uint4*)&lds[b][bwi[g]] = sb[s][g];
  };

  ffrag acc[RT][CT];
#pragma unroll
  for (int rt = 0; rt < RT; ++rt)
#pragma unroll
    for (int ct = 0; ct < CT; ++ct) acc[rt][ct] = ffrag{0.f, 0.f, 0.f, 0.f};

  // ---- prologue ----
  LOAD(0, 0);
  if (NK > 1) LOAD(1, 1);
  WRITE(0, 0);
  __syncthreads();

  // ---- pipelined k-loop: one barrier per step, loads 2 steps ahead ----
#pragma unroll
  for (int i = 0; i < NK; ++i) {
    if (i + 2 < NK) LOAD(i + 2, i & 1);          // issue-early (regs)
    bfrag a[RT];
#pragma unroll
    for (int rt = 0; rt < RT; ++rt) a[rt] = *(const bfrag*)&lds[i & 1][ard[rt]];
#pragma unroll
    for (int ct = 0; ct < CT; ++ct) {
      bfrag bf = *(const bfrag*)&lds[i & 1][brd[ct]];
#pragma unroll
      for (int rt = 0; rt < RT; ++rt)
        acc[rt][ct] = __builtin_amdgcn_mfma_f32_16x16x32_bf16(a[rt], bf, acc[rt][ct], 0, 0, 0);
    }
    if (i + 1 < NK) {
      WRITE((i + 1) & 1, (i + 1) & 1);           // write-late (after compute)
      __syncthreads();
    }
  }

  // ---- epilogue: bias + bf16 store (r0-identical) ----
#pragma unroll
  for (int rt = 0; rt < RT; ++rt)
#pragma unroll
    for (int ct = 0; ct < CT; ++ct) {
      const int n = n0 + wcol * (BN / 2) + ct * 16 + l16;
      const float bb = bc[n];
#pragma unroll
      for (int r = 0; r < 4; ++r) {
        const int m = m0 + wrow * 32 + rt * 16 + quad * 4 + r;
        if (m < M) out[(size_t)m * NN + n] = f2bf(acc[rt][ct][r] + bb);
      }
    }
}

// ---------------- fused per-node GAT edge pass (bf16, 4-edge unrolled) -------
template <int C>
__global__ void k_gat(const ushort_t* __restrict__ xlr, const int* __restrict__ row_ptr,
                      const int* __restrict__ csr_src, const float* __restrict__ att,
                      const float* __restrict__ bias, ushort_t* __restrict__ h) {
  constexpr int G = C / 8;          // lanes per edge group, 8 channels each
  constexpr int RS = 2 * C;         // row stride in ushorts
  int t = blockIdx.x * blockDim.x + threadIdx.x;
  int d = t / G;
  int lane = t - d * G;
  if (d >= N_NODES) return;
  float xr[8], a[8];
  unp8(*(const uint4*)(xlr + (size_t)d * RS + C + lane * 8), xr);
  *(float4*)&a[0] = *(const float4*)(att + lane * 8);
  *(float4*)&a[4] = *(const float4*)(att + lane * 8 + 4);
  float acc[8];
#pragma unroll
  for (int j = 0; j < 8; ++j) acc[j] = 0.f;
  float den = 0.f;
  const int e0 = row_ptr[d], e1 = row_ptr[d + 1];
  int i = e0;
  for (; i + 4 <= e1; i += 4) {
    uint4 u[4];
#pragma unroll
    for (int q = 0; q < 4; ++q)
      u[q] = *(const uint4*)(xlr + (size_t)csr_src[i + q] * RS + lane * 8);
    float xl[4][8];
#pragma unroll
    for (int q = 0; q < 4; ++q) unp8(u[q], xl[q]);
    float p[4] = {0.f, 0.f, 0.f, 0.f};
#pragma unroll
    for (int j = 0; j < 8; ++j) {
#pragma unroll
      for (int q = 0; q < 4; ++q) {
        float v = xl[q][j] + xr[j];
        v = v > 0.f ? v : NEG * v;
        p[q] += a[j] * v;
      }
    }
#pragma unroll
    for (int off = G / 2; off > 0; off >>= 1) {
#pragma unroll
      for (int q = 0; q < 4; ++q) p[q] += __shfl_xor(p[q], off, 64);
    }
    float ex[4];
#pragma unroll
    for (int q = 0; q < 4; ++q) ex[q] = expf(p[q]);
    den += (ex[0] + ex[1]) + (ex[2] + ex[3]);
#pragma unroll
    for (int j = 0; j < 8; ++j)
      acc[j] += (ex[0] * xl[0][j] + ex[1] * xl[1][j]) + (ex[2] * xl[2][j] + ex[3] * xl[3][j]);
  }
  for (; i < e1; ++i) {
    int s = csr_src[i];
    float xl[8];
    unp8(*(const uint4*)(xlr + (size_t)s * RS + lane * 8), xl);
    float p = 0.f;
#pragma unroll
    for (int j = 0; j < 8; ++j) {
      float v = xl[j] + xr[j];
      v = v > 0.f ? v : NEG * v;
      p += a[j] * v;
    }
#pragma unroll
    for (int off = G / 2; off > 0; off >>= 1) p += __shfl_xor(p, off, 64);
    float ex = expf(p);
    den += ex;
#pragma unroll
    for (int j = 0; j < 8; ++j) acc[j] += ex * xl[j];
  }
  float inv = 1.f / fmaxf(den, 1e-16f);
  float o[8];
#pragma unroll
  for (int j = 0; j < 8; ++j)
    o[j] = fmaxf(acc[j] * inv + bias[lane * 8 + j], 0.f);
  uint4 pk;
  pk.x = pack2(o[0], o[1]);
  pk.y = pack2(o[2], o[3]);
  pk.z = pack2(o[4], o[5]);
  pk.w = pack2(o[6], o[7]);
  *(uint4*)(h + (size_t)d * C + lane * 8) = pk;
}

// ---------------- pooling: sorted-batch run-accumulate (bf16 h3) -------------
__global__ void k_pool(const ushort_t* __restrict__ h3, const int* __restrict__ batch,
                       float* __restrict__ pooled, float* __restrict__ cnt) {
  constexpr int NPB = 1024;
  constexpr int NPT = NPB / 8;
  int c = threadIdx.x & 31;
  int r = threadIdx.x >> 5;
  int base = blockIdx.x * NPB + r * NPT;
  if (base >= N_NODES) return;
  int end = base + NPT;
  if (end > N_NODES) end = N_NODES;
  int cur_b = batch[base];
  float acc = 0.f, count = 0.f;
  for (int n = base; n < end; ++n) {
    int b = batch[n];
    if (b != cur_b) {
      atomicAdd(pooled + cur_b * HC2C + c, acc);
      if (c == 0) atomicAdd(cnt + cur_b, count);
      cur_b = b;
      acc = 0.f;
      count = 0.f;
    }
    acc += bf2f(h3[(size_t)n * HC2C + c]);
    count += 1.f;
  }
  atomicAdd(pooled + cur_b * HC2C + c, acc);
  if (c == 0) atomicAdd(cnt + cur_b, count);
}

// ---------------- fused tail ----------------
__global__ __launch_bounds__(256) void k_tail(
    const ushort_t* __restrict__ h3, const int* __restrict__ root,
    const float* __restrict__ pooled, const float* __restrict__ cnt,
    const float* __restrict__ linW, const float* __restrict__ linb,
    const float* __restrict__ X, const float* __restrict__ c1w,
    const float* __restrict__ c1b, const float* __restrict__ c2W,
    const float* __restrict__ c2b, const float* __restrict__ c3W,
    const float* __restrict__ c3b, const float* __restrict__ aW1,
    const float* __restrict__ ab1, const float* __restrict__ aW2,
    const float* __restrict__ mW1, const float* __restrict__ mb1,
    const float* __restrict__ mW2, const float* __restrict__ mb2,
    float* __restrict__ out) {
  constexpr int L = IN_F - 2;  // 254
  __shared__ float s_info[L];
  __shared__ float s_t1[HC1C];
  __shared__ float s_t2[HC1C / 2];
  __shared__ float s_e0[HC2C];  // sx
  __shared__ float s_e1[HC2C];  // tt
  const int b = blockIdx.x;
  const int tid = threadIdx.x;
  const int r = root[b];
  const float* xr = X + (size_t)r * IN_F;
  for (int i = tid; i < L; i += 256)
    s_info[i] = c1w[0] * xr[i] + c1w[1] * xr[i + 1] + c1w[2] * xr[i + 2] + c1b[0];
  __syncthreads();
  if (tid < HC1C) {
    float a = c2b[tid];
    for (int i = 0; i < L; ++i) a += c2W[tid * L + i] * s_info[i];
    s_t1[tid] = fmaxf(a, 0.f);
  }
  __syncthreads();
  if (tid < HC1C / 2) {
    float a = c3b[tid];
    for (int i = 0; i < HC1C; ++i) a += c3W[tid * HC1C + i] * s_t1[i];
    s_t2[tid] = fmaxf(a, 0.f);
  }
  __syncthreads();
  if (tid < HC2C) {
    float v = 0.5f * (s_t2[2 * tid] + s_t2[2 * tid + 1]);
    s_e1[tid] = fmaxf(v, 0.f);
  } else if (tid < 2 * HC2C) {
    int j = tid - HC2C;
    float inv = 1.f / fmaxf(cnt[b], 1.f);
    float a = linb[j];
    for (int c = 0; c < HC2C; ++c) a += bf2f(h3[(size_t)r * HC2C + c]) * linW[c * HC2C + j];
    for (int c = 0; c < HC2C; ++c) a += pooled[b * HC2C + c] * inv * linW[(HC2C + c) * HC2C + j];
    s_e0[j] = fmaxf(a, 0.f);
  }
  __syncthreads();
  if (tid == 0) {
    float w0 = 0.f, w1 = 0.f;
    for (int j = 0; j < 16; ++j) {
      float z0 = ab1[j], z1 = ab1[j];
      for (int c = 0; c < HC2C; ++c) {
        z0 += s_e0[c] * aW1[c * 16 + j];
        z1 += s_e1[c] * aW1[c * 16 + j];
      }
      w0 += tanhf(z0) * aW2[j];
      w1 += tanhf(z1) * aW2[j];
    }
    float mx = fmaxf(w0, w1);
    float x0 = expf(w0 - mx), x1 = expf(w1 - mx);
    float inv = 1.f / (x0 + x1);
    float b0 = x0 * inv, b1 = x1 * inv;
    float l0 = mb2[0], l1 = mb2[1];
    for (int j = 0; j < 16; ++j) {
      float z = mb1[j];
      for (int c = 0; c < HC2C; ++c) z += (b0 * s_e0[c] + b1 * s_e1[c]) * mW1[c * 16 + j];
      float tz = tanhf(z);
      l0 += tz * mW2[j * 2 + 0];
      l1 += tz * mW2[j * 2 + 1];
    }
    float m2 = fmaxf(l0, l1);
    float y0 = expf(l0 - m2), y1 = expf(l1 - m2);
    float is = 1.f / (y0 + y1);
    out[b * 2 + 0] = y0 * is;
    out[b * 2 + 1] = y1 * is;
  }
}

// ---------------- launcher ----------------
extern "C" void kernel_launch(void* const* d_in, const int* in_sizes, int n_in, void* d_out,
                              int out_size, void* d_ws, size_t ws_size, hipStream_t stream) {
  if (ws_size < WS_FLOATS * sizeof(float)) return;

  const float* s_x   = (const float*)d_in[0];
  const int*   edge  = (const int*)d_in[1];
  const int*   batch = (const int*)d_in[2];
  const int*   root  = (const int*)d_in[3];
  const float* Wv    = (const float*)d_in[8];
  const float* bv    = (const float*)d_in[9];
  const float* Wl1   = (const float*)d_in[10];
  const float* bl1   = (const float*)d_in[11];
  const float* Wr1   = (const float*)d_in[12];
  const float* br1   = (const float*)d_in[13];
  const float* att1  = (const float*)d_in[14];
  const float* bias1 = (const float*)d_in[15];
  const float* Wl2   = (const float*)d_in[16];
  const float* bl2   = (const float*)d_in[17];
  const float* Wr2   = (const float*)d_in[18];
  const float* br2   = (const float*)d_in[19];
  const float* att2  = (const float*)d_in[20];
  const float* bias2 = (const float*)d_in[21];
  const float* Wl3   = (const float*)d_in[22];
  const float* bl3   = (const float*)d_in[23];
  const float* Wr3   = (const float*)d_in[24];
  const float* br3   = (const float*)d_in[25];
  const float* att3  = (const float*)d_in[26];
  const float* bias3 = (const float*)d_in[27];
  const float* c1w   = (const float*)d_in[28];
  const float* c1b   = (const float*)d_in[29];
  const float* c2W   = (const float*)d_in[30];
  const float* c2b   = (const float*)d_in[31];
  const float* c3W   = (const float*)d_in[32];
  const float* c3b   = (const float*)d_in[33];
  const float* linW  = (const float*)d_in[34];
  const float* linb  = (const float*)d_in[35];
  const float* aW1   = (const float*)d_in[36];
  const float* ab1   = (const float*)d_in[37];
  const float* aW2   = (const float*)d_in[38];
  const float* mW1   = (const float*)d_in[39];
  const float* mb1   = (const float*)d_in[40];
  const float* mW2   = (const float*)d_in[41];
  const float* mb2   = (const float*)d_in[42];

  const int* src = edge;
  const int* dst = edge + N_EDGES;

  float*    ws      = (float*)d_ws;
  ushort_t* WT1     = (ushort_t*)(ws + OFF_WT1);
  ushort_t* WT2     = (ushort_t*)(ws + OFF_WT2);
  ushort_t* WT3     = (ushort_t*)(ws + OFF_WT3);
  float*    bc1     = ws + OFF_BC1;
  float*    bc2     = ws + OFF_BC2;
  float*    bc3     = ws + OFF_BC3;
  ushort_t* xlr     = (ushort_t*)(ws + OFF_XLR);
  ushort_t* hbuf    = (ushort_t*)(ws + OFF_H);
  int*      deg     = (int*)(ws + OFF_DEG);
  int*      row_ptr = (int*)(ws + OFF_ROWPTR);
  int*      cursor  = (int*)(ws + OFF_CURSOR);
  int*      blks    = (int*)(ws + OFF_BLKS);
  int*      blko    = (int*)(ws + OFF_BLKO);
  int*      csr_src = (int*)(ws + OFF_CSRSRC);
  float*    pooled  = ws + OFF_POOLED;
  float*    cnt     = ws + OFF_CNT;
  float*    out     = (float*)d_out;

  // ---- CSR build (by dst) ----
  hipMemsetAsync(deg, 0, N_NODES * sizeof(int), stream);
  k_hist<<<(N_EDGES + 255) / 256, 256, 0, stream>>>(dst, deg);
  k_scan_local<<<SCAN_NBLK, 256, 0, stream>>>(deg, row_ptr, blks);
  k_scan_blk<<<1, 512, 0, stream>>>(blks, blko);
  k_scan_add<<<SCAN_NBLK, 256, 0, stream>>>(row_ptr, blko, cursor);
  k_fill<<<(N_EDGES + 255) / 256, 256, 0, stream>>>(src, dst, cursor, csr_src);

  // ---- fused weight fold / pack ----
  k_pack_all<<<337, 256, 0, stream>>>(Wv, bv, Wl1, bl1, Wr1, br1, Wl2, bl2, Wr2, br2, Wl3,
                                      bl3, Wr3, br3, WT1, bc1, WT2, bc2, WT3, bc3);

  // ---- GAT layer 1 (K=256, N=256) ----
  k_gemm_bf16<256, 256, 128, true><<<dim3(MB64, 2), 256, 0, stream>>>(s_x, WT1, bc1, xlr,
                                                                      N_NODES);
  k_gat<128><<<(N_NODES * 16 + 255) / 256, 256, 0, stream>>>(xlr, row_ptr, csr_src, att1,
                                                             bias1, hbuf);

  // ---- GAT layer 2 (K=128, N=128) ----
  k_gemm_bf16<128, 128, 128, false><<<dim3(MB64, 1), 256, 0, stream>>>(hbuf, WT2, bc2, xlr,
                                                                       N_NODES);
  k_gat<64><<<(N_NODES * 8 + 255) / 256, 256, 0, stream>>>(xlr, row_ptr, csr_src, att2,
                                                           bias2, hbuf);

  // ---- GAT layer 3 (K=64, N=64) ----
  k_gemm_bf16<64, 64, 64, false><<<dim3(MB64, 1), 256, 0, stream>>>(hbuf, WT3, bc3, xlr,
                                                                    N_NODES);
  k_gat<32><<<(N_NODES * 4 + 255) / 256, 256, 0, stream>>>(xlr, row_ptr, csr_src, att3,
                                                           bias3, hbuf);

  // ---- pooling + fused tail ----
  hipMemsetAsync(pooled, 0, (NB * HC2C + NB) * sizeof(float), stream);
  k_pool<<<(N_NODES + 1023) / 1024, 256, 0, stream>>>(hbuf, batch, pooled, cnt);
  k_tail<<<NB, 256, 0, stream>>>(hbuf, root, pooled, cnt, linW, linb, s_x, c1w, c1b, c2W,
                                 c2b, c3W, c3b, aW1, ab1, aW2, mW1, mb1, mW2, mb2, out);
}

// Round 5
// 679.770 us; speedup vs baseline: 1.0007x; 1.0007x over previous
//
#include <hip/hip_runtime.h>
#include <hip/hip_bf16.h>
#include <math.h>

typedef unsigned short ushort_t;
typedef __attribute__((ext_vector_type(8))) short bfrag;   // 8 bf16 = 4 VGPRs
typedef __attribute__((ext_vector_type(4))) float ffrag;   // 4 fp32 acc

// ---------------- problem constants ----------------
constexpr int N_NODES = 100000;
constexpr int N_EDGES = 800000;
constexpr int NB      = 64;
constexpr int IN_F    = 256;
constexpr int HC1C    = 128;
constexpr int HC2C    = 32;
constexpr int SA_D    = 350;
constexpr float NEG   = 0.2f;

constexpr int SCAN_NBLK = (N_NODES + 255) / 256;  // 391
constexpr int MB64      = (N_NODES + 63) / 64;    // 1563

// ---------------- workspace layout (float-sized slots) ----------------
constexpr size_t OFF_WT1    = 0;                                   // 256*256 ush
constexpr size_t OFF_WT2    = OFF_WT1 + 65536;
constexpr size_t OFF_WT3    = OFF_WT2 + 16384;
constexpr size_t OFF_BC1    = OFF_WT3 + 4096;                      // 256
constexpr size_t OFF_BC2    = OFF_BC1 + 256;                       // 128
constexpr size_t OFF_BC3    = OFF_BC2 + 128;                       // 64
constexpr size_t OFF_XLR    = OFF_BC3 + 64;                        // N*256 bf16
constexpr size_t OFF_H      = OFF_XLR + (size_t)N_NODES * 256;     // N*128 bf16
constexpr size_t OFF_DEG    = OFF_H + (size_t)N_NODES * 128;       // N ints
constexpr size_t OFF_ROWPTR = OFF_DEG + N_NODES;                   // N+1 ints
constexpr size_t OFF_CURSOR = OFF_ROWPTR + N_NODES + 1;            // N ints
constexpr size_t OFF_BLKS   = OFF_CURSOR + N_NODES;                // 512 ints
constexpr size_t OFF_BLKO   = OFF_BLKS + 512;                      // 512 ints
constexpr size_t OFF_CSRSRC = OFF_BLKO + 512;                      // E ints
constexpr size_t OFF_POOLED = OFF_CSRSRC + N_EDGES;                // 64*32
constexpr size_t OFF_CNT    = OFF_POOLED + NB * HC2C;              // 64
constexpr size_t WS_FLOATS  = OFF_CNT + NB;

// ---------------- bf16 helpers ----------------
__device__ __forceinline__ ushort_t f2bf(float f) {  // RNE
  union { float f; unsigned int u; } a;
  a.f = f;
  unsigned int r = a.u + 0x7FFFu + ((a.u >> 16) & 1u);
  return (ushort_t)(r >> 16);
}
__device__ __forceinline__ float bf2f(ushort_t h) {
  union { unsigned int u; float f; } a;
  a.u = ((unsigned int)h) << 16;
  return a.f;
}
__device__ __forceinline__ float2 bfp(unsigned int u) {
  float2 r;
  r.x = __uint_as_float(u << 16);
  r.y = __uint_as_float(u & 0xFFFF0000u);
  return r;
}
__device__ __forceinline__ unsigned int pack2(float a, float b) {
  unsigned int ua = __float_as_uint(a);
  ua += 0x7FFFu + ((ua >> 16) & 1u);
  unsigned int ub = __float_as_uint(b);
  ub += 0x7FFFu + ((ub >> 16) & 1u);
  return __builtin_amdgcn_perm(ub, ua, 0x07060302u);
}
__device__ __forceinline__ void unp8(uint4 u, float* x) {
  float2 p0 = bfp(u.x), p1 = bfp(u.y), p2 = bfp(u.z), p3 = bfp(u.w);
  x[0] = p0.x; x[1] = p0.y; x[2] = p1.x; x[3] = p1.y;
  x[4] = p2.x; x[5] = p2.y; x[6] = p3.x; x[7] = p3.y;
}

// ---------------- fused weight fold/pack ----------------
__global__ void k_pack_all(const float* __restrict__ Wv, const float* __restrict__ bv,
                           const float* __restrict__ Wl1, const float* __restrict__ bl1,
                           const float* __restrict__ Wr1, const float* __restrict__ br1,
                           const float* __restrict__ Wl2, const float* __restrict__ bl2,
                           const float* __restrict__ Wr2, const float* __restrict__ br2,
                           const float* __restrict__ Wl3, const float* __restrict__ bl3,
                           const float* __restrict__ Wr3, const float* __restrict__ br3,
                           ushort_t* __restrict__ WT1, float* __restrict__ bc1,
                           ushort_t* __restrict__ WT2, float* __restrict__ bc2,
                           ushort_t* __restrict__ WT3, float* __restrict__ bc3) {
  int blk = blockIdx.x;
  int tid = threadIdx.x;
  if (blk < 256) {            // WT1 fold: (Wv@W{l,r}1)^T
    int t = blk * 256 + tid;
    int n = t & 255, k = t >> 8;
    const float* Wx = (n < 128) ? Wl1 : Wr1;
    int j = n & 127;
    float a = 0.f;
    for (int kk = 0; kk < SA_D; ++kk) a += Wv[k * SA_D + kk] * Wx[kk * 128 + j];
    WT1[(size_t)n * 256 + k] = f2bf(a);
  } else if (blk == 256) {    // bc1
    int n = tid;
    const float* Wx = (n < 128) ? Wl1 : Wr1;
    const float* bx = (n < 128) ? bl1 : br1;
    int j = n & 127;
    float a = bx[j];
    for (int kk = 0; kk < SA_D; ++kk) a += bv[kk] * Wx[kk * 128 + j];
    bc1[n] = a;
  } else if (blk < 321) {     // WT2 transpose pack
    int t = (blk - 257) * 256 + tid;
    int n = t & 127, k = t >> 7;
    if (t < 128) bc2[t] = (t < 64) ? bl2[t] : br2[t - 64];
    float v = (n < 64) ? Wl2[k * 64 + n] : Wr2[k * 64 + (n - 64)];
    WT2[(size_t)n * 128 + k] = f2bf(v);
  } else {                    // WT3 transpose pack
    int t = (blk - 321) * 256 + tid;
    int n = t & 63, k = t >> 6;
    if (t < 64) bc3[t] = (t < 32) ? bl3[t] : br3[t - 32];
    float v = (n < 32) ? Wl3[k * 32 + n] : Wr3[k * 32 + (n - 32)];
    WT3[(size_t)n * 64 + k] = f2bf(v);
  }
}

// ---------------- CSR build ----------------
__global__ void k_hist(const int* __restrict__ dst, int* __restrict__ deg) {
  int e = blockIdx.x * blockDim.x + threadIdx.x;
  if (e < N_EDGES) atomicAdd(deg + dst[e], 1);
}

__global__ void k_scan_local(const int* __restrict__ deg, int* __restrict__ row_ptr,
                             int* __restrict__ blk_sum) {
  __shared__ int sh[256];
  int t = threadIdx.x;
  int i = blockIdx.x * 256 + t;
  int v = (i < N_NODES) ? deg[i] : 0;
  sh[t] = v;
  __syncthreads();
  for (int off = 1; off < 256; off <<= 1) {
    int add = (t >= off) ? sh[t - off] : 0;
    __syncthreads();
    sh[t] += add;
    __syncthreads();
  }
  if (i < N_NODES) row_ptr[i] = sh[t] - v;
  if (t == 255) blk_sum[blockIdx.x] = sh[255];
}

__global__ void k_scan_blk(const int* __restrict__ blk_sum, int* __restrict__ blk_off) {
  __shared__ int sh[512];
  int t = threadIdx.x;
  int v = (t < SCAN_NBLK) ? blk_sum[t] : 0;
  sh[t] = v;
  __syncthreads();
  for (int off = 1; off < 512; off <<= 1) {
    int add = (t >= off) ? sh[t - off] : 0;
    __syncthreads();
    sh[t] += add;
    __syncthreads();
  }
  blk_off[t] = sh[t] - v;
}

__global__ void k_scan_add(int* __restrict__ row_ptr, const int* __restrict__ blk_off,
                           int* __restrict__ cursor) {
  int i = blockIdx.x * blockDim.x + threadIdx.x;
  if (i < N_NODES) {
    int v = row_ptr[i] + blk_off[i >> 8];
    row_ptr[i] = v;
    cursor[i] = v;
  }
  if (i == 0) row_ptr[N_NODES] = N_EDGES;
}

__global__ void k_fill(const int* __restrict__ src, const int* __restrict__ dst,
                       int* __restrict__ cursor, int* __restrict__ csr_src) {
  int e = blockIdx.x * blockDim.x + threadIdx.x;
  if (e >= N_EDGES) return;
  int pos = atomicAdd(cursor + dst[e], 1);
  csr_src[pos] = src[e];
}

// ---------------- reg-staged double-buffered MFMA GEMM (static slots) --------
// r4 proved the structure: reg-staged dbuf + 1 barrier/step + bf16-compact
// LDS + XOR swizzle -> 3.1 TB/s duty, 50% occ, 0 bank conflicts.  But its
// runtime-slot arrays (sf[2][..] indexed by i&1 via lambda params) went to
// SCRATCH (rule #20): VGPR=44, WRITE_SIZE 51->222MB, FETCH 101->127MB --
// every staged byte round-tripped through memory.  Fix: STATIC register
// naming.  Slots are named variable sets (A/B); the k-loop is unrolled two
// steps per iteration so even steps use slot A / buf 0, odd steps slot B /
// buf 1 -- every register reference is compile-time.  Macros (not lambdas)
// guarantee no captured-reference memory objects.  Barrier/hazard order,
// k-order, pack2, fragment mapping, acc chain identical to r4/r0.
template <int K, int NN, int BN, bool AF32>
__global__ __launch_bounds__(256, 4) void k_gemm_bf16(const void* __restrict__ xin,
                                                      const ushort_t* __restrict__ WT,
                                                      const float* __restrict__ bc,
                                                      ushort_t* __restrict__ out, int M) {
  constexpr int RT  = 2;             // 16-row tiles per wave
  constexpr int CT  = BN / 32;       // n-tiles per wave (colgroup = BN/2)
  constexpr int NK  = K / 32;        // k-steps (8 / 4 / 2 -- all even)
  constexpr int BGT = BN / 64;       // B 16B-granules per thread per step
  constexpr int BUS = 2048 + BN * 32;  // ushorts per LDS buffer (A 4KB + B)
  __shared__ __align__(16) ushort_t lds[2][BUS];

  const int tid  = threadIdx.x;
  const int wave = tid >> 6;
  const int lane = tid & 63;
  const int quad = lane >> 4;
  const int l16  = lane & 15;
  const int wrow = wave >> 1;
  const int wcol = wave & 1;
  const int m0   = blockIdx.x * 64;
  const int n0   = blockIdx.y * BN;

  const float*    af32 = (const float*)xin;
  const ushort_t* ab16 = (const ushort_t*)xin;

  // ---- staging indices: thread -> one A granule + BGT B granules ----
  // granule = 16B bf16 = 8 k-elems; line = 128B = 2 rows; phys = lg^(line&7)
  const int aline = tid >> 3, alg = tid & 7;
  const int arow  = aline * 2 + (alg >> 2);
  int am = m0 + arow;
  if (am >= M) am = M - 1;
  const size_t aoff = (size_t)am * K + (alg & 3) * 8;
  const int awi = aline * 64 + ((alg ^ (aline & 7)) * 8);

  size_t boff[BGT];
  int    bwi[BGT];
#pragma unroll
  for (int g = 0; g < BGT; ++g) {
    const int sB = g * 256 + tid;
    const int bline = sB >> 3, blg = sB & 7;
    const int brow = bline * 2 + (blg >> 2);
    boff[g] = (size_t)(n0 + brow) * K + (blg & 3) * 8;
    bwi[g]  = 2048 + bline * 64 + ((blg ^ (bline & 7)) * 8);
  }

  // ---- fragment read offsets (r2-proven mapping) ----
  int ard[RT];
#pragma unroll
  for (int rt = 0; rt < RT; ++rt) {
    const int row = wrow * 32 + rt * 16 + l16;
    const int line = row >> 1;
    ard[rt] = line * 64 + ((((row & 1) * 4 + quad) ^ (line & 7)) * 8);
  }
  int brd[CT];
#pragma unroll
  for (int ct = 0; ct < CT; ++ct) {
    const int rowb = wcol * (BN / 2) + ct * 16 + l16;
    const int lineb = rowb >> 1;
    brd[ct] = 2048 + lineb * 64 + ((((rowb & 1) * 4 + quad) ^ (lineb & 7)) * 8);
  }

  // ---- named register slots (NO runtime indexing -- rule #20) ----
  float4 sfA0, sfA1, sfB0, sfB1;
  uint4  shA, shB;
  uint4  sbA[BGT], sbB[BGT];

#define GLOAD(ks, SF0, SF1, SH, SB)                                        \
  do {                                                                     \
    if constexpr (AF32) {                                                  \
      SF0 = *(const float4*)(af32 + aoff + (size_t)(ks) * 32);             \
      SF1 = *(const float4*)(af32 + aoff + (size_t)(ks) * 32 + 4);         \
    } else {                                                               \
      SH = *(const uint4*)(ab16 + aoff + (size_t)(ks) * 32);               \
    }                                                                      \
    _Pragma("unroll")                                                      \
    for (int g = 0; g < BGT; ++g)                                          \
      SB[g] = *(const uint4*)(WT + boff[g] + (size_t)(ks) * 32);           \
  } while (0)

#define WLDS(SF0, SF1, SH, SB, BUF)                                        \
  do {                                                                     \
    uint4 w;                                                               \
    if constexpr (AF32) {                                                  \
      w.x = pack2(SF0.x, SF0.y);                                           \
      w.y = pack2(SF0.z, SF0.w);                                           \
      w.z = pack2(SF1.x, SF1.y);                                           \
      w.w = pack2(SF1.z, SF1.w);                                           \
    } else {                                                               \
      w = SH;                                                              \
    }                                                                      \
    *(uint4*)&lds[BUF][awi] = w;                                           \
    _Pragma("unroll")                                                      \
    for (int g = 0; g < BGT; ++g) *(uint4*)&lds[BUF][bwi[g]] = SB[g];      \
  } while (0)

#define KSTEP(BUF)                                                         \
  do {                                                                     \
    bfrag a0 = *(const bfrag*)&lds[BUF][ard[0]];                           \
    bfrag a1 = *(const bfrag*)&lds[BUF][ard[1]];                           \
    _Pragma("unroll")                                                      \
    for (int ct = 0; ct < CT; ++ct) {                                      \
      bfrag bf = *(const bfrag*)&lds[BUF][brd[ct]];                        \
      acc[0][ct] = __builtin_amdgcn_mfma_f32_16x16x32_bf16(a0, bf, acc[0][ct], 0, 0, 0); \
      acc[1][ct] = __builtin_amdgcn_mfma_f32_16x16x32_bf16(a1, bf, acc[1][ct], 0, 0, 0); \
    }                                                                      \
  } while (0)

  ffrag acc[RT][CT];
#pragma unroll
  for (int rt = 0; rt < RT; ++rt)
#pragma unroll
    for (int ct = 0; ct < CT; ++ct) acc[rt][ct] = ffrag{0.f, 0.f, 0.f, 0.f};

  // ---- prologue: tiles 0,1 -> slots A,B; tile 0 -> LDS buf 0 ----
  GLOAD(0, sfA0, sfA1, shA, sbA);
  GLOAD(1, sfB0, sfB1, shB, sbB);
  WLDS(sfA0, sfA1, shA, sbA, 0);
  __syncthreads();

  // ---- pipelined k-loop, 2 steps/iter, all slot refs static ----
#pragma unroll
  for (int ii = 0; ii < NK / 2; ++ii) {
    const int i = 2 * ii;
    if (i + 2 < NK) GLOAD(i + 2, sfA0, sfA1, shA, sbA);   // issue-early
    KSTEP(0);                                             // compute tile i
    WLDS(sfB0, sfB1, shB, sbB, 1);                        // tile i+1 -> buf 1
    __syncthreads();
    if (i + 3 < NK) GLOAD(i + 3, sfB0, sfB1, shB, sbB);   // issue-early
    KSTEP(1);                                             // compute tile i+1
    if (i + 2 < NK) {
      WLDS(sfA0, sfA1, shA, sbA, 0);                      // tile i+2 -> buf 0
      __syncthreads();
    }
  }
#undef GLOAD
#undef WLDS
#undef KSTEP

  // ---- epilogue: bias + bf16 store (r0-identical) ----
#pragma unroll
  for (int rt = 0; rt < RT; ++rt)
#pragma unroll
    for (int ct = 0; ct < CT; ++ct) {
      const int n = n0 + wcol * (BN / 2) + ct * 16 + l16;
      const float bb = bc[n];
#pragma unroll
      for (int r = 0; r < 4; ++r) {
        const int m = m0 + wrow * 32 + rt * 16 + quad * 4 + r;
        if (m < M) out[(size_t)m * NN + n] = f2bf(acc[rt][ct][r] + bb);
      }
    }
}

// ---------------- fused per-node GAT edge pass (bf16, 4-edge unrolled) -------
template <int C>
__global__ void k_gat(const ushort_t* __restrict__ xlr, const int* __restrict__ row_ptr,
                      const int* __restrict__ csr_src, const float* __restrict__ att,
                      const float* __restrict__ bias, ushort_t* __restrict__ h) {
  constexpr int G = C / 8;          // lanes per edge group, 8 channels each
  constexpr int RS = 2 * C;         // row stride in ushorts
  int t = blockIdx.x * blockDim.x + threadIdx.x;
  int d = t / G;
  int lane = t - d * G;
  if (d >= N_NODES) return;
  float xr[8], a[8];
  unp8(*(const uint4*)(xlr + (size_t)d * RS + C + lane * 8), xr);
  *(float4*)&a[0] = *(const float4*)(att + lane * 8);
  *(float4*)&a[4] = *(const float4*)(att + lane * 8 + 4);
  float acc[8];
#pragma unroll
  for (int j = 0; j < 8; ++j) acc[j] = 0.f;
  float den = 0.f;
  const int e0 = row_ptr[d], e1 = row_ptr[d + 1];
  int i = e0;
  for (; i + 4 <= e1; i += 4) {
    uint4 u[4];
#pragma unroll
    for (int q = 0; q < 4; ++q)
      u[q] = *(const uint4*)(xlr + (size_t)csr_src[i + q] * RS + lane * 8);
    float xl[4][8];
#pragma unroll
    for (int q = 0; q < 4; ++q) unp8(u[q], xl[q]);
    float p[4] = {0.f, 0.f, 0.f, 0.f};
#pragma unroll
    for (int j = 0; j < 8; ++j) {
#pragma unroll
      for (int q = 0; q < 4; ++q) {
        float v = xl[q][j] + xr[j];
        v = v > 0.f ? v : NEG * v;
        p[q] += a[j] * v;
      }
    }
#pragma unroll
    for (int off = G / 2; off > 0; off >>= 1) {
#pragma unroll
      for (int q = 0; q < 4; ++q) p[q] += __shfl_xor(p[q], off, 64);
    }
    float ex[4];
#pragma unroll
    for (int q = 0; q < 4; ++q) ex[q] = expf(p[q]);
    den += (ex[0] + ex[1]) + (ex[2] + ex[3]);
#pragma unroll
    for (int j = 0; j < 8; ++j)
      acc[j] += (ex[0] * xl[0][j] + ex[1] * xl[1][j]) + (ex[2] * xl[2][j] + ex[3] * xl[3][j]);
  }
  for (; i < e1; ++i) {
    int s = csr_src[i];
    float xl[8];
    unp8(*(const uint4*)(xlr + (size_t)s * RS + lane * 8), xl);
    float p = 0.f;
#pragma unroll
    for (int j = 0; j < 8; ++j) {
      float v = xl[j] + xr[j];
      v = v > 0.f ? v : NEG * v;
      p += a[j] * v;
    }
#pragma unroll
    for (int off = G / 2; off > 0; off >>= 1) p += __shfl_xor(p, off, 64);
    float ex = expf(p);
    den += ex;
#pragma unroll
    for (int j = 0; j < 8; ++j) acc[j] += ex * xl[j];
  }
  float inv = 1.f / fmaxf(den, 1e-16f);
  float o[8];
#pragma unroll
  for (int j = 0; j < 8; ++j)
    o[j] = fmaxf(acc[j] * inv + bias[lane * 8 + j], 0.f);
  uint4 pk;
  pk.x = pack2(o[0], o[1]);
  pk.y = pack2(o[2], o[3]);
  pk.z = pack2(o[4], o[5]);
  pk.w = pack2(o[6], o[7]);
  *(uint4*)(h + (size_t)d * C + lane * 8) = pk;
}

// ---------------- pooling: sorted-batch run-accumulate (bf16 h3) -------------
__global__ void k_pool(const ushort_t* __restrict__ h3, const int* __restrict__ batch,
                       float* __restrict__ pooled, float* __restrict__ cnt) {
  constexpr int NPB = 1024;
  constexpr int NPT = NPB / 8;
  int c = threadIdx.x & 31;
  int r = threadIdx.x >> 5;
  int base = blockIdx.x * NPB + r * NPT;
  if (base >= N_NODES) return;
  int end = base + NPT;
  if (end > N_NODES) end = N_NODES;
  int cur_b = batch[base];
  float acc = 0.f, count = 0.f;
  for (int n = base; n < end; ++n) {
    int b = batch[n];
    if (b != cur_b) {
      atomicAdd(pooled + cur_b * HC2C + c, acc);
      if (c == 0) atomicAdd(cnt + cur_b, count);
      cur_b = b;
      acc = 0.f;
      count = 0.f;
    }
    acc += bf2f(h3[(size_t)n * HC2C + c]);
    count += 1.f;
  }
  atomicAdd(pooled + cur_b * HC2C + c, acc);
  if (c == 0) atomicAdd(cnt + cur_b, count);
}

// ---------------- fused tail ----------------
__global__ __launch_bounds__(256) void k_tail(
    const ushort_t* __restrict__ h3, const int* __restrict__ root,
    const float* __restrict__ pooled, const float* __restrict__ cnt,
    const float* __restrict__ linW, const float* __restrict__ linb,
    const float* __restrict__ X, const float* __restrict__ c1w,
    const float* __restrict__ c1b, const float* __restrict__ c2W,
    const float* __restrict__ c2b, const float* __restrict__ c3W,
    const float* __restrict__ c3b, const float* __restrict__ aW1,
    const float* __restrict__ ab1, const float* __restrict__ aW2,
    const float* __restrict__ mW1, const float* __restrict__ mb1,
    const float* __restrict__ mW2, const float* __restrict__ mb2,
    float* __restrict__ out) {
  constexpr int L = IN_F - 2;  // 254
  __shared__ float s_info[L];
  __shared__ float s_t1[HC1C];
  __shared__ float s_t2[HC1C / 2];
  __shared__ float s_e0[HC2C];  // sx
  __shared__ float s_e1[HC2C];  // tt
  const int b = blockIdx.x;
  const int tid = threadIdx.x;
  const int r = root[b];
  const float* xr = X + (size_t)r * IN_F;
  for (int i = tid; i < L; i += 256)
    s_info[i] = c1w[0] * xr[i] + c1w[1] * xr[i + 1] + c1w[2] * xr[i + 2] + c1b[0];
  __syncthreads();
  if (tid < HC1C) {
    float a = c2b[tid];
    for (int i = 0; i < L; ++i) a += c2W[tid * L + i] * s_info[i];
    s_t1[tid] = fmaxf(a, 0.f);
  }
  __syncthreads();
  if (tid < HC1C / 2) {
    float a = c3b[tid];
    for (int i = 0; i < HC1C; ++i) a += c3W[tid * HC1C + i] * s_t1[i];
    s_t2[tid] = fmaxf(a, 0.f);
  }
  __syncthreads();
  if (tid < HC2C) {
    float v = 0.5f * (s_t2[2 * tid] + s_t2[2 * tid + 1]);
    s_e1[tid] = fmaxf(v, 0.f);
  } else if (tid < 2 * HC2C) {
    int j = tid - HC2C;
    float inv = 1.f / fmaxf(cnt[b], 1.f);
    float a = linb[j];
    for (int c = 0; c < HC2C; ++c) a += bf2f(h3[(size_t)r * HC2C + c]) * linW[c * HC2C + j];
    for (int c = 0; c < HC2C; ++c) a += pooled[b * HC2C + c] * inv * linW[(HC2C + c) * HC2C + j];
    s_e0[j] = fmaxf(a, 0.f);
  }
  __syncthreads();
  if (tid == 0) {
    float w0 = 0.f, w1 = 0.f;
    for (int j = 0; j < 16; ++j) {
      float z0 = ab1[j], z1 = ab1[j];
      for (int c = 0; c < HC2C; ++c) {
        z0 += s_e0[c] * aW1[c * 16 + j];
        z1 += s_e1[c] * aW1[c * 16 + j];
      }
      w0 += tanhf(z0) * aW2[j];
      w1 += tanhf(z1) * aW2[j];
    }
    float mx = fmaxf(w0, w1);
    float x0 = expf(w0 - mx), x1 = expf(w1 - mx);
    float inv = 1.f / (x0 + x1);
    float b0 = x0 * inv, b1 = x1 * inv;
    float l0 = mb2[0], l1 = mb2[1];
    for (int j = 0; j < 16; ++j) {
      float z = mb1[j];
      for (int c = 0; c < HC2C; ++c) z += (b0 * s_e0[c] + b1 * s_e1[c]) * mW1[c * 16 + j];
      float tz = tanhf(z);
      l0 += tz * mW2[j * 2 + 0];
      l1 += tz * mW2[j * 2 + 1];
    }
    float m2 = fmaxf(l0, l1);
    float y0 = expf(l0 - m2), y1 = expf(l1 - m2);
    float is = 1.f / (y0 + y1);
    out[b * 2 + 0] = y0 * is;
    out[b * 2 + 1] = y1 * is;
  }
}

// ---------------- launcher ----------------
extern "C" void kernel_launch(void* const* d_in, const int* in_sizes, int n_in, void* d_out,
                              int out_size, void* d_ws, size_t ws_size, hipStream_t stream) {
  if (ws_size < WS_FLOATS * sizeof(float)) return;

  const float* s_x   = (const float*)d_in[0];
  const int*   edge  = (const int*)d_in[1];
  const int*   batch = (const int*)d_in[2];
  const int*   root  = (const int*)d_in[3];
  const float* Wv    = (const float*)d_in[8];
  const float* bv    = (const float*)d_in[9];
  const float* Wl1   = (const float*)d_in[10];
  const float* bl1   = (const float*)d_in[11];
  const float* Wr1   = (const float*)d_in[12];
  const float* br1   = (const float*)d_in[13];
  const float* att1  = (const float*)d_in[14];
  const float* bias1 = (const float*)d_in[15];
  const float* Wl2   = (const float*)d_in[16];
  const float* bl2   = (const float*)d_in[17];
  const float* Wr2   = (const float*)d_in[18];
  const float* br2   = (const float*)d_in[19];
  const float* att2  = (const float*)d_in[20];
  const float* bias2 = (const float*)d_in[21];
  const float* Wl3   = (const float*)d_in[22];
  const float* bl3   = (const float*)d_in[23];
  const float* Wr3   = (const float*)d_in[24];
  const float* br3   = (const float*)d_in[25];
  const float* att3  = (const float*)d_in[26];
  const float* bias3 = (const float*)d_in[27];
  const float* c1w   = (const float*)d_in[28];
  const float* c1b   = (const float*)d_in[29];
  const float* c2W   = (const float*)d_in[30];
  const float* c2b   = (const float*)d_in[31];
  const float* c3W   = (const float*)d_in[32];
  const float* c3b   = (const float*)d_in[33];
  const float* linW  = (const float*)d_in[34];
  const float* linb  = (const float*)d_in[35];
  const float* aW1   = (const float*)d_in[36];
  const float* ab1   = (const float*)d_in[37];
  const float* aW2   = (const float*)d_in[38];
  const float* mW1   = (const float*)d_in[39];
  const float* mb1   = (const float*)d_in[40];
  const float* mW2   = (const float*)d_in[41];
  const float* mb2   = (const float*)d_in[42];

  const int* src = edge;
  const int* dst = edge + N_EDGES;

  float*    ws      = (float*)d_ws;
  ushort_t* WT1     = (ushort_t*)(ws + OFF_WT1);
  ushort_t* WT2     = (ushort_t*)(ws + OFF_WT2);
  ushort_t* WT3     = (ushort_t*)(ws + OFF_WT3);
  float*    bc1     = ws + OFF_BC1;
  float*    bc2     = ws + OFF_BC2;
  float*    bc3     = ws + OFF_BC3;
  ushort_t* xlr     = (ushort_t*)(ws + OFF_XLR);
  ushort_t* hbuf    = (ushort_t*)(ws + OFF_H);
  int*      deg     = (int*)(ws + OFF_DEG);
  int*      row_ptr = (int*)(ws + OFF_ROWPTR);
  int*      cursor  = (int*)(ws + OFF_CURSOR);
  int*      blks    = (int*)(ws + OFF_BLKS);
  int*      blko    = (int*)(ws + OFF_BLKO);
  int*      csr_src = (int*)(ws + OFF_CSRSRC);
  float*    pooled  = ws + OFF_POOLED;
  float*    cnt     = ws + OFF_CNT;
  float*    out     = (float*)d_out;

  // ---- CSR build (by dst) ----
  hipMemsetAsync(deg, 0, N_NODES * sizeof(int), stream);
  k_hist<<<(N_EDGES + 255) / 256, 256, 0, stream>>>(dst, deg);
  k_scan_local<<<SCAN_NBLK, 256, 0, stream>>>(deg, row_ptr, blks);
  k_scan_blk<<<1, 512, 0, stream>>>(blks, blko);
  k_scan_add<<<SCAN_NBLK, 256, 0, stream>>>(row_ptr, blko, cursor);
  k_fill<<<(N_EDGES + 255) / 256, 256, 0, stream>>>(src, dst, cursor, csr_src);

  // ---- fused weight fold / pack ----
  k_pack_all<<<337, 256, 0, stream>>>(Wv, bv, Wl1, bl1, Wr1, br1, Wl2, bl2, Wr2, br2, Wl3,
                                      bl3, Wr3, br3, WT1, bc1, WT2, bc2, WT3, bc3);

  // ---- GAT layer 1 (K=256, N=256) ----
  k_gemm_bf16<256, 256, 128, true><<<dim3(MB64, 2), 256, 0, stream>>>(s_x, WT1, bc1, xlr,
                                                                      N_NODES);
  k_gat<128><<<(N_NODES * 16 + 255) / 256, 256, 0, stream>>>(xlr, row_ptr, csr_src, att1,
                                                             bias1, hbuf);

  // ---- GAT layer 2 (K=128, N=128) ----
  k_gemm_bf16<128, 128, 128, false><<<dim3(MB64, 1), 256, 0, stream>>>(hbuf, WT2, bc2, xlr,
                                                                       N_NODES);
  k_gat<64><<<(N_NODES * 8 + 255) / 256, 256, 0, stream>>>(xlr, row_ptr, csr_src, att2,
                                                           bias2, hbuf);

  // ---- GAT layer 3 (K=64, N=64) ----
  k_gemm_bf16<64, 64, 64, false><<<dim3(MB64, 1), 256, 0, stream>>>(hbuf, WT3, bc3, xlr,
                                                                    N_NODES);
  k_gat<32><<<(N_NODES * 4 + 255) / 256, 256, 0, stream>>>(xlr, row_ptr, csr_src, att3,
                                                           bias3, hbuf);

  // ---- pooling + fused tail ----
  hipMemsetAsync(pooled, 0, (NB * HC2C + NB) * sizeof(float), stream);
  k_pool<<<(N_NODES + 1023) / 1024, 256, 0, stream>>>(hbuf, batch, pooled, cnt);
  k_tail<<<NB, 256, 0, stream>>>(hbuf, root, pooled, cnt, linW, linb, s_x, c1w, c1b, c2W,
                                 c2b, c3W, c3b, aW1, ab1, aW2, mW1, mb1, mW2, mb2, out);
}

// Round 6
// 624.375 us; speedup vs baseline: 1.0895x; 1.0887x over previous
//
#include <hip/hip_runtime.h>
#include <hip/hip_bf16.h>
#include <math.h>

typedef unsigned short ushort_t;
typedef __attribute__((ext_vector_type(8))) short bfrag;   // 8 bf16 = 4 VGPRs
typedef __attribute__((ext_vector_type(4))) float ffrag;   // 4 fp32 acc

#define GLOBAL_AS __attribute__((address_space(1)))
#define LDS_AS    __attribute__((address_space(3)))

// ---------------- problem constants ----------------
constexpr int N_NODES = 100000;
constexpr int N_EDGES = 800000;
constexpr int NB      = 64;
constexpr int IN_F    = 256;
constexpr int HC1C    = 128;
constexpr int HC2C    = 32;
constexpr int SA_D    = 350;
constexpr float NEG   = 0.2f;

constexpr int SCAN_NBLK = (N_NODES + 255) / 256;  // 391
constexpr int MB64      = (N_NODES + 63) / 64;    // 1563

// ---------------- workspace layout (float-sized slots) ----------------
constexpr size_t OFF_WT1    = 0;                                   // 256*256 ush
constexpr size_t OFF_WT2    = OFF_WT1 + 65536;
constexpr size_t OFF_WT3    = OFF_WT2 + 16384;
constexpr size_t OFF_BC1    = OFF_WT3 + 4096;                      // 256
constexpr size_t OFF_BC2    = OFF_BC1 + 256;                       // 128
constexpr size_t OFF_BC3    = OFF_BC2 + 128;                       // 64
constexpr size_t OFF_XLR    = OFF_BC3 + 64;                        // N*256 bf16
constexpr size_t OFF_H      = OFF_XLR + (size_t)N_NODES * 256;     // N*128 bf16
constexpr size_t OFF_DEG    = OFF_H + (size_t)N_NODES * 128;       // N ints
constexpr size_t OFF_ROWPTR = OFF_DEG + N_NODES;                   // N+1 ints
constexpr size_t OFF_CURSOR = OFF_ROWPTR + N_NODES + 1;            // N ints
constexpr size_t OFF_BLKS   = OFF_CURSOR + N_NODES;                // 512 ints
constexpr size_t OFF_BLKO   = OFF_BLKS + 512;                      // 512 ints
constexpr size_t OFF_CSRSRC = OFF_BLKO + 512;                      // E ints
constexpr size_t OFF_POOLED = OFF_CSRSRC + N_EDGES;                // 64*32
constexpr size_t OFF_CNT    = OFF_POOLED + NB * HC2C;              // 64
constexpr size_t WS_FLOATS  = OFF_CNT + NB;

// ---------------- bf16 helpers ----------------
__device__ __forceinline__ ushort_t f2bf(float f) {  // RNE
  union { float f; unsigned int u; } a;
  a.f = f;
  unsigned int r = a.u + 0x7FFFu + ((a.u >> 16) & 1u);
  return (ushort_t)(r >> 16);
}
__device__ __forceinline__ float bf2f(ushort_t h) {
  union { unsigned int u; float f; } a;
  a.u = ((unsigned int)h) << 16;
  return a.f;
}
__device__ __forceinline__ float2 bfp(unsigned int u) {
  float2 r;
  r.x = __uint_as_float(u << 16);
  r.y = __uint_as_float(u & 0xFFFF0000u);
  return r;
}
__device__ __forceinline__ unsigned int pack2(float a, float b) {
  unsigned int ua = __float_as_uint(a);
  ua += 0x7FFFu + ((ua >> 16) & 1u);
  unsigned int ub = __float_as_uint(b);
  ub += 0x7FFFu + ((ub >> 16) & 1u);
  return __builtin_amdgcn_perm(ub, ua, 0x07060302u);
}
__device__ __forceinline__ void unp8(uint4 u, float* x) {
  float2 p0 = bfp(u.x), p1 = bfp(u.y), p2 = bfp(u.z), p3 = bfp(u.w);
  x[0] = p0.x; x[1] = p0.y; x[2] = p1.x; x[3] = p1.y;
  x[4] = p2.x; x[5] = p2.y; x[6] = p3.x; x[7] = p3.y;
}

// ---------------- fused weight fold/pack ----------------
__global__ void k_pack_all(const float* __restrict__ Wv, const float* __restrict__ bv,
                           const float* __restrict__ Wl1, const float* __restrict__ bl1,
                           const float* __restrict__ Wr1, const float* __restrict__ br1,
                           const float* __restrict__ Wl2, const float* __restrict__ bl2,
                           const float* __restrict__ Wr2, const float* __restrict__ br2,
                           const float* __restrict__ Wl3, const float* __restrict__ bl3,
                           const float* __restrict__ Wr3, const float* __restrict__ br3,
                           ushort_t* __restrict__ WT1, float* __restrict__ bc1,
                           ushort_t* __restrict__ WT2, float* __restrict__ bc2,
                           ushort_t* __restrict__ WT3, float* __restrict__ bc3) {
  int blk = blockIdx.x;
  int tid = threadIdx.x;
  if (blk < 256) {            // WT1 fold: (Wv@W{l,r}1)^T
    int t = blk * 256 + tid;
    int n = t & 255, k = t >> 8;
    const float* Wx = (n < 128) ? Wl1 : Wr1;
    int j = n & 127;
    float a = 0.f;
    for (int kk = 0; kk < SA_D; ++kk) a += Wv[k * SA_D + kk] * Wx[kk * 128 + j];
    WT1[(size_t)n * 256 + k] = f2bf(a);
  } else if (blk == 256) {    // bc1
    int n = tid;
    const float* Wx = (n < 128) ? Wl1 : Wr1;
    const float* bx = (n < 128) ? bl1 : br1;
    int j = n & 127;
    float a = bx[j];
    for (int kk = 0; kk < SA_D; ++kk) a += bv[kk] * Wx[kk * 128 + j];
    bc1[n] = a;
  } else if (blk < 321) {     // WT2 transpose pack
    int t = (blk - 257) * 256 + tid;
    int n = t & 127, k = t >> 7;
    if (t < 128) bc2[t] = (t < 64) ? bl2[t] : br2[t - 64];
    float v = (n < 64) ? Wl2[k * 64 + n] : Wr2[k * 64 + (n - 64)];
    WT2[(size_t)n * 128 + k] = f2bf(v);
  } else {                    // WT3 transpose pack
    int t = (blk - 321) * 256 + tid;
    int n = t & 63, k = t >> 6;
    if (t < 64) bc3[t] = (t < 32) ? bl3[t] : br3[t - 32];
    float v = (n < 32) ? Wl3[k * 32 + n] : Wr3[k * 32 + (n - 32)];
    WT3[(size_t)n * 64 + k] = f2bf(v);
  }
}

// ---------------- CSR build ----------------
__global__ void k_hist(const int* __restrict__ dst, int* __restrict__ deg) {
  int e = blockIdx.x * blockDim.x + threadIdx.x;
  if (e < N_EDGES) atomicAdd(deg + dst[e], 1);
}

__global__ void k_scan_local(const int* __restrict__ deg, int* __restrict__ row_ptr,
                             int* __restrict__ blk_sum) {
  __shared__ int sh[256];
  int t = threadIdx.x;
  int i = blockIdx.x * 256 + t;
  int v = (i < N_NODES) ? deg[i] : 0;
  sh[t] = v;
  __syncthreads();
  for (int off = 1; off < 256; off <<= 1) {
    int add = (t >= off) ? sh[t - off] : 0;
    __syncthreads();
    sh[t] += add;
    __syncthreads();
  }
  if (i < N_NODES) row_ptr[i] = sh[t] - v;
  if (t == 255) blk_sum[blockIdx.x] = sh[255];
}

__global__ void k_scan_blk(const int* __restrict__ blk_sum, int* __restrict__ blk_off) {
  __shared__ int sh[512];
  int t = threadIdx.x;
  int v = (t < SCAN_NBLK) ? blk_sum[t] : 0;
  sh[t] = v;
  __syncthreads();
  for (int off = 1; off < 512; off <<= 1) {
    int add = (t >= off) ? sh[t - off] : 0;
    __syncthreads();
    sh[t] += add;
    __syncthreads();
  }
  blk_off[t] = sh[t] - v;
}

__global__ void k_scan_add(int* __restrict__ row_ptr, const int* __restrict__ blk_off,
                           int* __restrict__ cursor) {
  int i = blockIdx.x * blockDim.x + threadIdx.x;
  if (i < N_NODES) {
    int v = row_ptr[i] + blk_off[i >> 8];
    row_ptr[i] = v;
    cursor[i] = v;
  }
  if (i == 0) row_ptr[N_NODES] = N_EDGES;
}

__global__ void k_fill(const int* __restrict__ src, const int* __restrict__ dst,
                       int* __restrict__ cursor, int* __restrict__ csr_src) {
  int e = blockIdx.x * blockDim.x + threadIdx.x;
  if (e >= N_EDGES) return;
  int pos = atomicAdd(cursor + dst[e], 1);
  csr_src[pos] = src[e];
}

// ---------------- hybrid-staged double-buffered MFMA GEMM ----------------
// Evidence through r5: traffic-CLEAN staging = gl_lds (r2: WRITE 52MB) or
// immediate load->pack->ds_write (r0: WRITE 51MB).  Traffic-DIRTY staging =
// registers holding staged tiles across __syncthreads (r4/r5: WRITE 222MB,
// VGPR=44 -> compiler sent the slots to scratch; static naming didn't help).
// r4 also proved the pipeline shape itself reaches 3.1 TB/s duty at 50% occ
// with 0 bank conflicts.  This round keeps that shape but builds it ONLY
// from the clean mechanisms:
//  * B: global_load_lds for step i+1 issued BEFORE compute(i); zero VGPR;
//    in flight across the compute phase; drained by the one barrier/step.
//  * A fp32 (layer 1): reg path with liveness confined to ONE iteration and
//    crossing NO barrier: ALOAD(i+1) -> KSTEP(i) -> APACK+ds_write -> bar.
//    A loads issued before B's gl_lds so the pack's counted vmcnt leaves B
//    outstanding.
//  * A bf16 (layers 2/3): global_load_lds as well -- no staging regs at all.
// LDS stays bf16-compact (24KB) -> 4 blocks/CU; r2/r4-verified XOR granule
// swizzle (phys = lg ^ (line&7), line = 2 rows).  Fragment maps, k-order,
// pack2, acc chain verbatim from r4 (absmax 0).
template <int K, int NN, int BN, bool AF32>
__global__ __launch_bounds__(256, 4) void k_gemm_bf16(const void* __restrict__ xin,
                                                      const ushort_t* __restrict__ WT,
                                                      const float* __restrict__ bc,
                                                      ushort_t* __restrict__ out, int M) {
  constexpr int RT  = 2;                        // 16-row tiles per wave
  constexpr int CT  = BN / 32;                  // n-tiles per wave
  constexpr int NK  = K / 32;                   // k-steps
  constexpr int BGI = (BN * 32 * 2 / 16) / 256; // B gl_lds iters (128->2, 64->1)
  constexpr int BUS = 2048 + BN * 32;           // ushorts per buffer
  __shared__ __align__(16) ushort_t lds[2][BUS];

  const int tid  = threadIdx.x;
  const int wave = tid >> 6;
  const int lane = tid & 63;
  const int quad = lane >> 4;
  const int l16  = lane & 15;
  const int wrow = wave >> 1;
  const int wcol = wave & 1;
  const int m0   = blockIdx.x * 64;
  const int n0   = blockIdx.y * BN;

  const float*    af32 = (const float*)xin;
  const ushort_t* ab16 = (const ushort_t*)xin;

  // ---- A indices ----
  // fp32 reg path: thread owns 8 consecutive k (32B) of one row; ds_write
  // to XOR-swizzled granule (r4-verified).
  const int aline = tid >> 3, alg = tid & 7;
  const int arow  = aline * 2 + (alg >> 2);
  int am = m0 + arow;
  if (am >= M) am = M - 1;
  const size_t aoff = (size_t)am * K + (alg & 3) * 8;
  const int awi = aline * 64 + ((alg ^ (aline & 7)) * 8);
  // bf16 gl_lds path: linear LDS slot tid, pre-swizzled global source
  // (r2-verified mapping).
  const int ainner = (tid & 7) ^ (aline & 7);
  const int arow2  = aline * 2 + (ainner >> 2);
  int am2 = m0 + arow2;
  if (am2 >= M) am2 = M - 1;
  const size_t aoff2 = (size_t)am2 * K + (ainner & 3) * 8;

  // ---- B gl_lds source offsets (linear LDS slot, pre-swizzled source) ----
  size_t boff[BGI];
#pragma unroll
  for (int g = 0; g < BGI; ++g) {
    const int s = g * 256 + tid;
    const int bline = s >> 3;
    const int binner = (s & 7) ^ (bline & 7);
    const int brow = bline * 2 + (binner >> 2);
    boff[g] = (size_t)(n0 + brow) * K + (binner & 3) * 8;
  }

  // ---- fragment read offsets (r4-verified) ----
  int ard[RT];
#pragma unroll
  for (int rt = 0; rt < RT; ++rt) {
    const int row = wrow * 32 + rt * 16 + l16;
    const int line = row >> 1;
    ard[rt] = line * 64 + ((((row & 1) * 4 + quad) ^ (line & 7)) * 8);
  }
  int brd[CT];
#pragma unroll
  for (int ct = 0; ct < CT; ++ct) {
    const int rowb = wcol * (BN / 2) + ct * 16 + l16;
    const int lineb = rowb >> 1;
    brd[ct] = 2048 + lineb * 64 + ((((rowb & 1) * 4 + quad) ^ (lineb & 7)) * 8);
  }

  // single named A slot -- lives load -> pack within one iteration only
  float4 af0, af1;

#define ALOAD(ks)                                                          \
  do {                                                                     \
    af0 = *(const float4*)(af32 + aoff + (size_t)(ks) * 32);               \
    af1 = *(const float4*)(af32 + aoff + (size_t)(ks) * 32 + 4);           \
  } while (0)

#define APACK(BUF)                                                         \
  do {                                                                     \
    uint4 w;                                                               \
    w.x = pack2(af0.x, af0.y);                                             \
    w.y = pack2(af0.z, af0.w);                                             \
    w.z = pack2(af1.x, af1.y);                                             \
    w.w = pack2(af1.z, af1.w);                                             \
    *(uint4*)&lds[BUF][awi] = w;                                           \
  } while (0)

#define STAGE_A_GL(ks, BUF)                                                \
  __builtin_amdgcn_global_load_lds(                                        \
      (const GLOBAL_AS unsigned int*)(ab16 + aoff2 + (size_t)(ks) * 32),   \
      (LDS_AS unsigned int*)&lds[BUF][(size_t)(wave * 64) * 8], 16, 0, 0)

#define STAGE_B(ks, BUF)                                                   \
  do {                                                                     \
    _Pragma("unroll")                                                      \
    for (int g = 0; g < BGI; ++g)                                          \
      __builtin_amdgcn_global_load_lds(                                    \
          (const GLOBAL_AS unsigned int*)(WT + boff[g] + (size_t)(ks) * 32), \
          (LDS_AS unsigned int*)&lds[BUF][2048 + (size_t)((g * 256 + wave * 64) * 8)], \
          16, 0, 0);                                                       \
  } while (0)

#define KSTEP(BUF)                                                         \
  do {                                                                     \
    bfrag a0 = *(const bfrag*)&lds[BUF][ard[0]];                           \
    bfrag a1 = *(const bfrag*)&lds[BUF][ard[1]];                           \
    _Pragma("unroll")                                                      \
    for (int ct = 0; ct < CT; ++ct) {                                      \
      bfrag bf = *(const bfrag*)&lds[BUF][brd[ct]];                        \
      acc[0][ct] = __builtin_amdgcn_mfma_f32_16x16x32_bf16(a0, bf, acc[0][ct], 0, 0, 0); \
      acc[1][ct] = __builtin_amdgcn_mfma_f32_16x16x32_bf16(a1, bf, acc[1][ct], 0, 0, 0); \
    }                                                                      \
  } while (0)

  ffrag acc[RT][CT];
#pragma unroll
  for (int rt = 0; rt < RT; ++rt)
#pragma unroll
    for (int ct = 0; ct < CT; ++ct) acc[rt][ct] = ffrag{0.f, 0.f, 0.f, 0.f};

  // ---- prologue: stage step 0 into buf 0 ----
  if constexpr (AF32) {
    ALOAD(0);
    STAGE_B(0, 0);
    APACK(0);          // vmcnt leaves the gl_lds outstanding (issued after A)
  } else {
    STAGE_A_GL(0, 0);
    STAGE_B(0, 0);
  }
  __syncthreads();     // drains all staging for step 0

  // ---- pipelined k-loop: one barrier per step ----
#pragma unroll
  for (int i = 0; i < NK; ++i) {
    const int cur = i & 1;
    if (i + 1 < NK) {
      if constexpr (AF32) ALOAD(i + 1);          // A first (see APACK note)
      else                STAGE_A_GL(i + 1, cur ^ 1);
      STAGE_B(i + 1, cur ^ 1);
    }
    KSTEP(cur);                                  // hides staging latency
    if (i + 1 < NK) {
      if constexpr (AF32) APACK(cur ^ 1);        // pack after compute
      __syncthreads();                           // buf cur^1 fully staged
    }
  }
#undef ALOAD
#undef APACK
#undef STAGE_A_GL
#undef STAGE_B
#undef KSTEP

  // ---- epilogue: bias + bf16 store (r0-identical) ----
#pragma unroll
  for (int rt = 0; rt < RT; ++rt)
#pragma unroll
    for (int ct = 0; ct < CT; ++ct) {
      const int n = n0 + wcol * (BN / 2) + ct * 16 + l16;
      const float bb = bc[n];
#pragma unroll
      for (int r = 0; r < 4; ++r) {
        const int m = m0 + wrow * 32 + rt * 16 + quad * 4 + r;
        if (m < M) out[(size_t)m * NN + n] = f2bf(acc[rt][ct][r] + bb);
      }
    }
}

// ---------------- fused per-node GAT edge pass (bf16, 4-edge unrolled) -------
template <int C>
__global__ void k_gat(const ushort_t* __restrict__ xlr, const int* __restrict__ row_ptr,
                      const int* __restrict__ csr_src, const float* __restrict__ att,
                      const float* __restrict__ bias, ushort_t* __restrict__ h) {
  constexpr int G = C / 8;          // lanes per edge group, 8 channels each
  constexpr int RS = 2 * C;         // row stride in ushorts
  int t = blockIdx.x * blockDim.x + threadIdx.x;
  int d = t / G;
  int lane = t - d * G;
  if (d >= N_NODES) return;
  float xr[8], a[8];
  unp8(*(const uint4*)(xlr + (size_t)d * RS + C + lane * 8), xr);
  *(float4*)&a[0] = *(const float4*)(att + lane * 8);
  *(float4*)&a[4] = *(const float4*)(att + lane * 8 + 4);
  float acc[8];
#pragma unroll
  for (int j = 0; j < 8; ++j) acc[j] = 0.f;
  float den = 0.f;
  const int e0 = row_ptr[d], e1 = row_ptr[d + 1];
  int i = e0;
  for (; i + 4 <= e1; i += 4) {
    uint4 u[4];
#pragma unroll
    for (int q = 0; q < 4; ++q)
      u[q] = *(const uint4*)(xlr + (size_t)csr_src[i + q] * RS + lane * 8);
    float xl[4][8];
#pragma unroll
    for (int q = 0; q < 4; ++q) unp8(u[q], xl[q]);
    float p[4] = {0.f, 0.f, 0.f, 0.f};
#pragma unroll
    for (int j = 0; j < 8; ++j) {
#pragma unroll
      for (int q = 0; q < 4; ++q) {
        float v = xl[q][j] + xr[j];
        v = v > 0.f ? v : NEG * v;
        p[q] += a[j] * v;
      }
    }
#pragma unroll
    for (int off = G / 2; off > 0; off >>= 1) {
#pragma unroll
      for (int q = 0; q < 4; ++q) p[q] += __shfl_xor(p[q], off, 64);
    }
    float ex[4];
#pragma unroll
    for (int q = 0; q < 4; ++q) ex[q] = expf(p[q]);
    den += (ex[0] + ex[1]) + (ex[2] + ex[3]);
#pragma unroll
    for (int j = 0; j < 8; ++j)
      acc[j] += (ex[0] * xl[0][j] + ex[1] * xl[1][j]) + (ex[2] * xl[2][j] + ex[3] * xl[3][j]);
  }
  for (; i < e1; ++i) {
    int s = csr_src[i];
    float xl[8];
    unp8(*(const uint4*)(xlr + (size_t)s * RS + lane * 8), xl);
    float p = 0.f;
#pragma unroll
    for (int j = 0; j < 8; ++j) {
      float v = xl[j] + xr[j];
      v = v > 0.f ? v : NEG * v;
      p += a[j] * v;
    }
#pragma unroll
    for (int off = G / 2; off > 0; off >>= 1) p += __shfl_xor(p, off, 64);
    float ex = expf(p);
    den += ex;
#pragma unroll
    for (int j = 0; j < 8; ++j) acc[j] += ex * xl[j];
  }
  float inv = 1.f / fmaxf(den, 1e-16f);
  float o[8];
#pragma unroll
  for (int j = 0; j < 8; ++j)
    o[j] = fmaxf(acc[j] * inv + bias[lane * 8 + j], 0.f);
  uint4 pk;
  pk.x = pack2(o[0], o[1]);
  pk.y = pack2(o[2], o[3]);
  pk.z = pack2(o[4], o[5]);
  pk.w = pack2(o[6], o[7]);
  *(uint4*)(h + (size_t)d * C + lane * 8) = pk;
}

// ---------------- pooling: sorted-batch run-accumulate (bf16 h3) -------------
__global__ void k_pool(const ushort_t* __restrict__ h3, const int* __restrict__ batch,
                       float* __restrict__ pooled, float* __restrict__ cnt) {
  constexpr int NPB = 1024;
  constexpr int NPT = NPB / 8;
  int c = threadIdx.x & 31;
  int r = threadIdx.x >> 5;
  int base = blockIdx.x * NPB + r * NPT;
  if (base >= N_NODES) return;
  int end = base + NPT;
  if (end > N_NODES) end = N_NODES;
  int cur_b = batch[base];
  float acc = 0.f, count = 0.f;
  for (int n = base; n < end; ++n) {
    int b = batch[n];
    if (b != cur_b) {
      atomicAdd(pooled + cur_b * HC2C + c, acc);
      if (c == 0) atomicAdd(cnt + cur_b, count);
      cur_b = b;
      acc = 0.f;
      count = 0.f;
    }
    acc += bf2f(h3[(size_t)n * HC2C + c]);
    count += 1.f;
  }
  atomicAdd(pooled + cur_b * HC2C + c, acc);
  if (c == 0) atomicAdd(cnt + cur_b, count);
}

// ---------------- fused tail ----------------
__global__ __launch_bounds__(256) void k_tail(
    const ushort_t* __restrict__ h3, const int* __restrict__ root,
    const float* __restrict__ pooled, const float* __restrict__ cnt,
    const float* __restrict__ linW, const float* __restrict__ linb,
    const float* __restrict__ X, const float* __restrict__ c1w,
    const float* __restrict__ c1b, const float* __restrict__ c2W,
    const float* __restrict__ c2b, const float* __restrict__ c3W,
    const float* __restrict__ c3b, const float* __restrict__ aW1,
    const float* __restrict__ ab1, const float* __restrict__ aW2,
    const float* __restrict__ mW1, const float* __restrict__ mb1,
    const float* __restrict__ mW2, const float* __restrict__ mb2,
    float* __restrict__ out) {
  constexpr int L = IN_F - 2;  // 254
  __shared__ float s_info[L];
  __shared__ float s_t1[HC1C];
  __shared__ float s_t2[HC1C / 2];
  __shared__ float s_e0[HC2C];  // sx
  __shared__ float s_e1[HC2C];  // tt
  const int b = blockIdx.x;
  const int tid = threadIdx.x;
  const int r = root[b];
  const float* xr = X + (size_t)r * IN_F;
  for (int i = tid; i < L; i += 256)
    s_info[i] = c1w[0] * xr[i] + c1w[1] * xr[i + 1] + c1w[2] * xr[i + 2] + c1b[0];
  __syncthreads();
  if (tid < HC1C) {
    float a = c2b[tid];
    for (int i = 0; i < L; ++i) a += c2W[tid * L + i] * s_info[i];
    s_t1[tid] = fmaxf(a, 0.f);
  }
  __syncthreads();
  if (tid < HC1C / 2) {
    float a = c3b[tid];
    for (int i = 0; i < HC1C; ++i) a += c3W[tid * HC1C + i] * s_t1[i];
    s_t2[tid] = fmaxf(a, 0.f);
  }
  __syncthreads();
  if (tid < HC2C) {
    float v = 0.5f * (s_t2[2 * tid] + s_t2[2 * tid + 1]);
    s_e1[tid] = fmaxf(v, 0.f);
  } else if (tid < 2 * HC2C) {
    int j = tid - HC2C;
    float inv = 1.f / fmaxf(cnt[b], 1.f);
    float a = linb[j];
    for (int c = 0; c < HC2C; ++c) a += bf2f(h3[(size_t)r * HC2C + c]) * linW[c * HC2C + j];
    for (int c = 0; c < HC2C; ++c) a += pooled[b * HC2C + c] * inv * linW[(HC2C + c) * HC2C + j];
    s_e0[j] = fmaxf(a, 0.f);
  }
  __syncthreads();
  if (tid == 0) {
    float w0 = 0.f, w1 = 0.f;
    for (int j = 0; j < 16; ++j) {
      float z0 = ab1[j], z1 = ab1[j];
      for (int c = 0; c < HC2C; ++c) {
        z0 += s_e0[c] * aW1[c * 16 + j];
        z1 += s_e1[c] * aW1[c * 16 + j];
      }
      w0 += tanhf(z0) * aW2[j];
      w1 += tanhf(z1) * aW2[j];
    }
    float mx = fmaxf(w0, w1);
    float x0 = expf(w0 - mx), x1 = expf(w1 - mx);
    float inv = 1.f / (x0 + x1);
    float b0 = x0 * inv, b1 = x1 * inv;
    float l0 = mb2[0], l1 = mb2[1];
    for (int j = 0; j < 16; ++j) {
      float z = mb1[j];
      for (int c = 0; c < HC2C; ++c) z += (b0 * s_e0[c] + b1 * s_e1[c]) * mW1[c * 16 + j];
      float tz = tanhf(z);
      l0 += tz * mW2[j * 2 + 0];
      l1 += tz * mW2[j * 2 + 1];
    }
    float m2 = fmaxf(l0, l1);
    float y0 = expf(l0 - m2), y1 = expf(l1 - m2);
    float is = 1.f / (y0 + y1);
    out[b * 2 + 0] = y0 * is;
    out[b * 2 + 1] = y1 * is;
  }
}

// ---------------- launcher ----------------
extern "C" void kernel_launch(void* const* d_in, const int* in_sizes, int n_in, void* d_out,
                              int out_size, void* d_ws, size_t ws_size, hipStream_t stream) {
  if (ws_size < WS_FLOATS * sizeof(float)) return;

  const float* s_x   = (const float*)d_in[0];
  const int*   edge  = (const int*)d_in[1];
  const int*   batch = (const int*)d_in[2];
  const int*   root  = (const int*)d_in[3];
  const float* Wv    = (const float*)d_in[8];
  const float* bv    = (const float*)d_in[9];
  const float* Wl1   = (const float*)d_in[10];
  const float* bl1   = (const float*)d_in[11];
  const float* Wr1   = (const float*)d_in[12];
  const float* br1   = (const float*)d_in[13];
  const float* att1  = (const float*)d_in[14];
  const float* bias1 = (const float*)d_in[15];
  const float* Wl2   = (const float*)d_in[16];
  const float* bl2   = (const float*)d_in[17];
  const float* Wr2   = (const float*)d_in[18];
  const float* br2   = (const float*)d_in[19];
  const float* att2  = (const float*)d_in[20];
  const float* bias2 = (const float*)d_in[21];
  const float* Wl3   = (const float*)d_in[22];
  const float* bl3   = (const float*)d_in[23];
  const float* Wr3   = (const float*)d_in[24];
  const float* br3   = (const float*)d_in[25];
  const float* att3  = (const float*)d_in[26];
  const float* bias3 = (const float*)d_in[27];
  const float* c1w   = (const float*)d_in[28];
  const float* c1b   = (const float*)d_in[29];
  const float* c2W   = (const float*)d_in[30];
  const float* c2b   = (const float*)d_in[31];
  const float* c3W   = (const float*)d_in[32];
  const float* c3b   = (const float*)d_in[33];
  const float* linW  = (const float*)d_in[34];
  const float* linb  = (const float*)d_in[35];
  const float* aW1   = (const float*)d_in[36];
  const float* ab1   = (const float*)d_in[37];
  const float* aW2   = (const float*)d_in[38];
  const float* mW1   = (const float*)d_in[39];
  const float* mb1   = (const float*)d_in[40];
  const float* mW2   = (const float*)d_in[41];
  const float* mb2   = (const float*)d_in[42];

  const int* src = edge;
  const int* dst = edge + N_EDGES;

  float*    ws      = (float*)d_ws;
  ushort_t* WT1     = (ushort_t*)(ws + OFF_WT1);
  ushort_t* WT2     = (ushort_t*)(ws + OFF_WT2);
  ushort_t* WT3     = (ushort_t*)(ws + OFF_WT3);
  float*    bc1     = ws + OFF_BC1;
  float*    bc2     = ws + OFF_BC2;
  float*    bc3     = ws + OFF_BC3;
  ushort_t* xlr     = (ushort_t*)(ws + OFF_XLR);
  ushort_t* hbuf    = (ushort_t*)(ws + OFF_H);
  int*      deg     = (int*)(ws + OFF_DEG);
  int*      row_ptr = (int*)(ws + OFF_ROWPTR);
  int*      cursor  = (int*)(ws + OFF_CURSOR);
  int*      blks    = (int*)(ws + OFF_BLKS);
  int*      blko    = (int*)(ws + OFF_BLKO);
  int*      csr_src = (int*)(ws + OFF_CSRSRC);
  float*    pooled  = ws + OFF_POOLED;
  float*    cnt     = ws + OFF_CNT;
  float*    out     = (float*)d_out;

  // ---- CSR build (by dst) ----
  hipMemsetAsync(deg, 0, N_NODES * sizeof(int), stream);
  k_hist<<<(N_EDGES + 255) / 256, 256, 0, stream>>>(dst, deg);
  k_scan_local<<<SCAN_NBLK, 256, 0, stream>>>(deg, row_ptr, blks);
  k_scan_blk<<<1, 512, 0, stream>>>(blks, blko);
  k_scan_add<<<SCAN_NBLK, 256, 0, stream>>>(row_ptr, blko, cursor);
  k_fill<<<(N_EDGES + 255) / 256, 256, 0, stream>>>(src, dst, cursor, csr_src);

  // ---- fused weight fold / pack ----
  k_pack_all<<<337, 256, 0, stream>>>(Wv, bv, Wl1, bl1, Wr1, br1, Wl2, bl2, Wr2, br2, Wl3,
                                      bl3, Wr3, br3, WT1, bc1, WT2, bc2, WT3, bc3);

  // ---- GAT layer 1 (K=256, N=256) ----
  k_gemm_bf16<256, 256, 128, true><<<dim3(MB64, 2), 256, 0, stream>>>(s_x, WT1, bc1, xlr,
                                                                      N_NODES);
  k_gat<128><<<(N_NODES * 16 + 255) / 256, 256, 0, stream>>>(xlr, row_ptr, csr_src, att1,
                                                             bias1, hbuf);

  // ---- GAT layer 2 (K=128, N=128) ----
  k_gemm_bf16<128, 128, 128, false><<<dim3(MB64, 1), 256, 0, stream>>>(hbuf, WT2, bc2, xlr,
                                                                       N_NODES);
  k_gat<64><<<(N_NODES * 8 + 255) / 256, 256, 0, stream>>>(xlr, row_ptr, csr_src, att2,
                                                           bias2, hbuf);

  // ---- GAT layer 3 (K=64, N=64) ----
  k_gemm_bf16<64, 64, 64, false><<<dim3(MB64, 1), 256, 0, stream>>>(hbuf, WT3, bc3, xlr,
                                                                    N_NODES);
  k_gat<32><<<(N_NODES * 4 + 255) / 256, 256, 0, stream>>>(xlr, row_ptr, csr_src, att3,
                                                           bias3, hbuf);

  // ---- pooling + fused tail ----
  hipMemsetAsync(pooled, 0, (NB * HC2C + NB) * sizeof(float), stream);
  k_pool<<<(N_NODES + 1023) / 1024, 256, 0, stream>>>(hbuf, batch, pooled, cnt);
  k_tail<<<NB, 256, 0, stream>>>(hbuf, root, pooled, cnt, linW, linb, s_x, c1w, c1b, c2W,
                                 c2b, c3W, c3b, aW1, ab1, aW2, mW1, mb1, mW2, mb2, out);
}